// Round 1
// baseline (886.038 us; speedup 1.0000x reference)
//
#include <hip/hip_runtime.h>
#include <math.h>

#define N_NODES 50000
#define N_EDGES 1600000
#define D1 128
#define D2 40

// ---------------------------------------------------------------------------
// edge_index dtype detection: if the buffer is int64 (little-endian, values
// < 2^31), every odd 32-bit word of the row array is 0. For a genuine int32
// buffer the odd words are random row ids — P(all zero) ~ 0.
__global__ void detect64_k(const unsigned int* __restrict__ ei, int* __restrict__ flag) {
    __shared__ int any;
    if (threadIdx.x == 0) any = 0;
    __syncthreads();
    for (int i = threadIdx.x; i < 2048; i += 256) {
        if (ei[2 * i + 1] != 0u) any = 1;
    }
    __syncthreads();
    if (threadIdx.x == 0) flag[0] = any ? 0 : 1;  // 1 == int64 layout
}

__device__ __forceinline__ int edge_row(const unsigned int* ei, int e, int is64) {
    return (int)(is64 ? ei[2 * e] : ei[e]);
}
__device__ __forceinline__ int edge_col(const unsigned int* ei, int e, int is64) {
    return (int)(is64 ? ei[2 * (N_EDGES + e)] : ei[N_EDGES + e]);
}

// ---------------------------------------------------------------------------
__global__ void zero_k(int* __restrict__ p, int n) {
    int i = blockIdx.x * blockDim.x + threadIdx.x;
    if (i < n) p[i] = 0;
}

__global__ void hist_k(const unsigned int* __restrict__ ei, const int* __restrict__ flag,
                       int* __restrict__ cnt) {
    int is64 = flag[0];
    int stride = gridDim.x * blockDim.x;
    for (int e = blockIdx.x * blockDim.x + threadIdx.x; e < N_EDGES; e += stride) {
        atomicAdd(&cnt[edge_row(ei, e, is64)], 1);
    }
}

// single-block exclusive scan of cnt[0..N) -> rowptr; cnt is overwritten with
// the same exclusive prefix (reused as the running-offset array for scatter).
__global__ __launch_bounds__(1024) void scan_k(int* __restrict__ cnt, int* __restrict__ rowptr) {
    __shared__ int s[1024];
    int tid = threadIdx.x;
    int carry = 0;
    for (int base = 0; base < N_NODES; base += 1024) {
        int i = base + tid;
        int v = (i < N_NODES) ? cnt[i] : 0;
        s[tid] = v;
        __syncthreads();
        for (int off = 1; off < 1024; off <<= 1) {
            int add = (tid >= off) ? s[tid - off] : 0;
            __syncthreads();
            s[tid] += add;
            __syncthreads();
        }
        if (i < N_NODES) {
            int excl = carry + s[tid] - v;
            rowptr[i] = excl;
            cnt[i] = excl;
        }
        int total = s[1023];
        __syncthreads();
        carry += total;
    }
    if (tid == 0) rowptr[N_NODES] = carry;
}

__global__ void scatter_k(const unsigned int* __restrict__ ei, const float* __restrict__ ew,
                          const int* __restrict__ flag, int* __restrict__ off,
                          int* __restrict__ colS, float* __restrict__ wS) {
    int is64 = flag[0];
    int stride = gridDim.x * blockDim.x;
    for (int e = blockIdx.x * blockDim.x + threadIdx.x; e < N_EDGES; e += stride) {
        int r = edge_row(ei, e, is64);
        int p = atomicAdd(&off[r], 1);
        colS[p] = edge_col(ei, e, is64);
        wS[p] = ew[e];
    }
}

// ---------------------------------------------------------------------------
// A = x @ W1   (50000x128 * 128x128), f32 VALU, LDS-tiled.
__global__ __launch_bounds__(256) void gemm1_k(const float* __restrict__ x,
                                               const float* __restrict__ W1,
                                               float* __restrict__ A) {
    __shared__ float xs[16][128];
    __shared__ float ws[32][128];
    int t = threadIdx.x;
    int row0 = blockIdx.x * 16;
#pragma unroll
    for (int i = 0; i < 8; ++i) {
        int idx = t + i * 256;
        xs[idx >> 7][idx & 127] = x[(row0 + (idx >> 7)) * D1 + (idx & 127)];
    }
    int c = t & 127;
    int rg = (t >> 7) * 8;
    float acc[8] = {0, 0, 0, 0, 0, 0, 0, 0};
    for (int kb = 0; kb < 128; kb += 32) {
        __syncthreads();
#pragma unroll
        for (int i = 0; i < 16; ++i) {
            int idx = t + i * 256;
            ws[idx >> 7][idx & 127] = W1[(kb + (idx >> 7)) * D1 + (idx & 127)];
        }
        __syncthreads();
#pragma unroll
        for (int k = 0; k < 32; ++k) {
            float w = ws[k][c];
#pragma unroll
            for (int r = 0; r < 8; ++r) acc[r] += xs[rg + r][kb + k] * w;
        }
    }
#pragma unroll
    for (int r = 0; r < 8; ++r) A[(row0 + rg + r) * D1 + c] = acc[r];
}

// B[r] = sum_j w_j * A[col_j]   (CSR, 2 rows/block, 128 lanes/row, no atomics)
__global__ __launch_bounds__(256) void spmm1_k(const float* __restrict__ A,
                                               const int* __restrict__ rowptr,
                                               const int* __restrict__ colS,
                                               const float* __restrict__ wS,
                                               float* __restrict__ B) {
    int t = threadIdx.x;
    int r = blockIdx.x * 2 + (t >> 7);
    int lane = t & 127;
    int s = rowptr[r], e = rowptr[r + 1];
    float acc = 0.f;
    for (int j = s; j < e; ++j) {
        int c = colS[j];
        float w = wS[j];
        acc += w * A[c * D1 + lane];
    }
    B[r * D1 + lane] = acc;
}

// G = relu(B + b1) @ W2   (bias1 + relu fused into the LDS load)
__global__ __launch_bounds__(256) void gemm2_k(const float* __restrict__ B,
                                               const float* __restrict__ b1,
                                               const float* __restrict__ W2,
                                               float* __restrict__ G) {
    __shared__ float hs[32][128];
    __shared__ float w2s[128 * 40];
    int t = threadIdx.x;
    int row0 = blockIdx.x * 32;
#pragma unroll
    for (int i = 0; i < 16; ++i) {
        int idx = t + i * 256;
        int r = idx >> 7, k = idx & 127;
        float v = 0.f;
        if (row0 + r < N_NODES) v = B[(row0 + r) * D1 + k] + b1[k];
        hs[r][k] = v > 0.f ? v : 0.f;
    }
    for (int idx = t; idx < D1 * D2; idx += 256) w2s[idx] = W2[idx];
    __syncthreads();
    for (int oi = t; oi < 32 * D2; oi += 256) {
        int r = oi / D2, c = oi % D2;
        float acc = 0.f;
#pragma unroll
        for (int k = 0; k < 128; ++k) acc += hs[r][k] * w2s[k * D2 + c];
        if (row0 + r < N_NODES) G[(row0 + r) * D2 + c] = acc;
    }
}

// D[r] = sum_j w_j * G[col_j]   (4 rows/block, 64-lane groups, lanes 0..39 active)
__global__ __launch_bounds__(256) void spmm2_k(const float* __restrict__ G,
                                               const int* __restrict__ rowptr,
                                               const int* __restrict__ colS,
                                               const float* __restrict__ wS,
                                               float* __restrict__ D) {
    int t = threadIdx.x;
    int r = blockIdx.x * 4 + (t >> 6);
    int lane = t & 63;
    int s = rowptr[r], e = rowptr[r + 1];
    if (lane < D2) {
        float acc = 0.f;
        for (int j = s; j < e; ++j) acc += wS[j] * G[colS[j] * D2 + lane];
        D[r * D2 + lane] = acc;
    }
}

// out = log_softmax(D + b2)  — one wave per row
__global__ __launch_bounds__(256) void lsm_k(const float* __restrict__ D,
                                             const float* __restrict__ b2,
                                             float* __restrict__ out) {
    int t = threadIdx.x;
    int r = blockIdx.x * 4 + (t >> 6);
    int lane = t & 63;
    float v = (lane < D2) ? D[r * D2 + lane] + b2[lane] : -INFINITY;
    float m = v;
#pragma unroll
    for (int off = 32; off >= 1; off >>= 1) m = fmaxf(m, __shfl_xor(m, off));
    float ex = (lane < D2) ? expf(v - m) : 0.f;
    float sum = ex;
#pragma unroll
    for (int off = 32; off >= 1; off >>= 1) sum += __shfl_xor(sum, off);
    if (lane < D2) out[r * D2 + lane] = v - m - logf(sum);
}

// ---------------------------------------------------------------------------
extern "C" void kernel_launch(void* const* d_in, const int* in_sizes, int n_in,
                              void* d_out, int out_size, void* d_ws, size_t ws_size,
                              hipStream_t stream) {
    const float* x = (const float*)d_in[0];
    const unsigned int* ei = (const unsigned int*)d_in[1];
    const float* ew = (const float*)d_in[2];
    const float* W1 = (const float*)d_in[3];
    const float* b1 = (const float*)d_in[4];
    const float* W2 = (const float*)d_in[5];
    const float* b2 = (const float*)d_in[6];
    float* out = (float*)d_out;

    char* w = (char*)d_ws;
    float* A = (float*)w;                          // 25.6 MB  XW1 (reused as G)
    float* B = (float*)(w + 25600000);             // 25.6 MB  spmm1 out
    float* G = A;                                  // reuse: A dead after spmm1
    float* D = (float*)(w + 51200000);             // 8 MB     spmm2 out
    int* rowptr = (int*)(w + 59200000);            // (N+1)*4
    int* cnt = (int*)(w + 59400448);               // N*4, doubles as offsets
    int* colS = (int*)(w + 59600448);              // E*4
    float* wS = (float*)(w + 66000448);            // E*4
    int* flag = (int*)(w + 72400448);              // 4

    detect64_k<<<1, 256, 0, stream>>>(ei, flag);
    zero_k<<<(N_NODES + 255) / 256, 256, 0, stream>>>(cnt, N_NODES);
    hist_k<<<4096, 256, 0, stream>>>(ei, flag, cnt);
    scan_k<<<1, 1024, 0, stream>>>(cnt, rowptr);
    scatter_k<<<4096, 256, 0, stream>>>(ei, ew, flag, cnt, colS, wS);

    gemm1_k<<<N_NODES / 16, 256, 0, stream>>>(x, W1, A);
    spmm1_k<<<N_NODES / 2, 256, 0, stream>>>(A, rowptr, colS, wS, B);
    gemm2_k<<<(N_NODES + 31) / 32, 256, 0, stream>>>(B, b1, W2, G);
    spmm2_k<<<N_NODES / 4, 256, 0, stream>>>(G, rowptr, colS, wS, D);
    lsm_k<<<N_NODES / 4, 256, 0, stream>>>(D, b2, out);
}

// Round 2
// 561.020 us; speedup vs baseline: 1.5793x; 1.5793x over previous
//
#include <hip/hip_runtime.h>
#include <math.h>

#define N_NODES 50000
#define N_EDGES 1600000
#define D1 128
#define D2 40
#define NTILE 196  // ceil(N_NODES/256)

// ---------------------------------------------------------------------------
// edge_index dtype detection: if the buffer is int64 (little-endian, values
// < 2^31), every odd 32-bit word of the row array is 0.
__global__ void detect64_k(const unsigned int* __restrict__ ei, int* __restrict__ flag) {
    __shared__ int any;
    if (threadIdx.x == 0) any = 0;
    __syncthreads();
    for (int i = threadIdx.x; i < 2048; i += 256) {
        if (ei[2 * i + 1] != 0u) any = 1;
    }
    __syncthreads();
    if (threadIdx.x == 0) flag[0] = any ? 0 : 1;  // 1 == int64 layout
}

__device__ __forceinline__ int edge_row(const unsigned int* ei, int e, int is64) {
    return (int)(is64 ? ei[2 * e] : ei[e]);
}
__device__ __forceinline__ int edge_col(const unsigned int* ei, int e, int is64) {
    return (int)(is64 ? ei[2 * (N_EDGES + e)] : ei[N_EDGES + e]);
}

// ---------------------------------------------------------------------------
__global__ void zero_k(int* __restrict__ p, int n) {
    int i = blockIdx.x * blockDim.x + threadIdx.x;
    if (i < n) p[i] = 0;
}

__global__ void hist_k(const unsigned int* __restrict__ ei, const int* __restrict__ flag,
                       int* __restrict__ cnt) {
    int is64 = flag[0];
    int stride = gridDim.x * blockDim.x;
    for (int e = blockIdx.x * blockDim.x + threadIdx.x; e < N_EDGES; e += stride) {
        atomicAdd(&cnt[edge_row(ei, e, is64)], 1);
    }
}

// --- hierarchical exclusive scan: scan1 (per-tile) -> scan2 (tile sums) -> scan3 (add)
__global__ __launch_bounds__(256) void scan1_k(const int* __restrict__ cnt,
                                               int* __restrict__ part, int* __restrict__ tsum) {
    __shared__ int s[256];
    int tid = threadIdx.x;
    int i = blockIdx.x * 256 + tid;
    int v = (i < N_NODES) ? cnt[i] : 0;
    s[tid] = v;
    __syncthreads();
    for (int off = 1; off < 256; off <<= 1) {
        int add = (tid >= off) ? s[tid - off] : 0;
        __syncthreads();
        s[tid] += add;
        __syncthreads();
    }
    if (i < N_NODES) part[i] = s[tid] - v;  // exclusive within tile
    if (tid == 255) tsum[blockIdx.x] = s[255];
}

__global__ __launch_bounds__(256) void scan2_k(const int* __restrict__ tsum,
                                               int* __restrict__ toff, int* __restrict__ total) {
    __shared__ int s[256];
    int tid = threadIdx.x;
    int v = (tid < NTILE) ? tsum[tid] : 0;
    s[tid] = v;
    __syncthreads();
    for (int off = 1; off < 256; off <<= 1) {
        int add = (tid >= off) ? s[tid - off] : 0;
        __syncthreads();
        s[tid] += add;
        __syncthreads();
    }
    if (tid < NTILE) toff[tid] = s[tid] - v;
    if (tid == 255) total[0] = s[255];  // == rowptr[N]
}

__global__ __launch_bounds__(256) void scan3_k(int* __restrict__ rowptr, const int* __restrict__ toff,
                                               int* __restrict__ cnt) {
    int i = blockIdx.x * 256 + threadIdx.x;
    if (i < N_NODES) {
        int v = rowptr[i] + toff[i >> 8];
        rowptr[i] = v;
        cnt[i] = v;  // running offsets for scatter
    }
}

__global__ void scatter_k(const unsigned int* __restrict__ ei, const float* __restrict__ ew,
                          const int* __restrict__ flag, int* __restrict__ off,
                          int* __restrict__ colS, float* __restrict__ wS) {
    int is64 = flag[0];
    int stride = gridDim.x * blockDim.x;
    for (int e = blockIdx.x * blockDim.x + threadIdx.x; e < N_EDGES; e += stride) {
        int r = edge_row(ei, e, is64);
        int p = atomicAdd(&off[r], 1);
        colS[p] = edge_col(ei, e, is64);
        wS[p] = ew[e];
    }
}

// ---------------------------------------------------------------------------
// A = x @ W1   (50000x128 * 128x128), f32 VALU, LDS-tiled.
__global__ __launch_bounds__(256) void gemm1_k(const float* __restrict__ x,
                                               const float* __restrict__ W1,
                                               float* __restrict__ A) {
    __shared__ float xs[16][128];
    __shared__ float ws[32][128];
    int t = threadIdx.x;
    int row0 = blockIdx.x * 16;
#pragma unroll
    for (int i = 0; i < 8; ++i) {
        int idx = t + i * 256;
        xs[idx >> 7][idx & 127] = x[(row0 + (idx >> 7)) * D1 + (idx & 127)];
    }
    int c = t & 127;
    int rg = (t >> 7) * 8;
    float acc[8] = {0, 0, 0, 0, 0, 0, 0, 0};
    for (int kb = 0; kb < 128; kb += 32) {
        __syncthreads();
#pragma unroll
        for (int i = 0; i < 16; ++i) {
            int idx = t + i * 256;
            ws[idx >> 7][idx & 127] = W1[(kb + (idx >> 7)) * D1 + (idx & 127)];
        }
        __syncthreads();
#pragma unroll
        for (int k = 0; k < 32; ++k) {
            float w = ws[k][c];
#pragma unroll
            for (int r = 0; r < 8; ++r) acc[r] += xs[rg + r][kb + k] * w;
        }
    }
#pragma unroll
    for (int r = 0; r < 8; ++r) A[(row0 + rg + r) * D1 + c] = acc[r];
}

// B[r] = sum_j w_j * A[col_j]
// One row per wave. Each half-wave (32 lanes) processes one edge with float4
// gathers (512 B per instruction); 2 edges in flight per iter + unroll 4.
__global__ __launch_bounds__(256) void spmm1_k(const float* __restrict__ A,
                                               const int* __restrict__ rowptr,
                                               const int* __restrict__ colS,
                                               const float* __restrict__ wS,
                                               float* __restrict__ B) {
    int t = threadIdx.x;
    int r = blockIdx.x * 4 + (t >> 6);
    int lane = t & 63;
    int half = lane >> 5;
    int cg = lane & 31;
    int s = rowptr[r], e = rowptr[r + 1];
    float4 acc = {0.f, 0.f, 0.f, 0.f};
#pragma unroll 4
    for (int j = s + half; j < e; j += 2) {
        int c = colS[j];
        float w = wS[j];
        float4 v = *reinterpret_cast<const float4*>(&A[c * D1 + cg * 4]);
        acc.x += w * v.x;
        acc.y += w * v.y;
        acc.z += w * v.z;
        acc.w += w * v.w;
    }
    acc.x += __shfl_xor(acc.x, 32);
    acc.y += __shfl_xor(acc.y, 32);
    acc.z += __shfl_xor(acc.z, 32);
    acc.w += __shfl_xor(acc.w, 32);
    if (half == 0) *reinterpret_cast<float4*>(&B[r * D1 + cg * 4]) = acc;
}

// G = relu(B + b1) @ W2   (bias1 + relu fused into the LDS load)
__global__ __launch_bounds__(256) void gemm2_k(const float* __restrict__ B,
                                               const float* __restrict__ b1,
                                               const float* __restrict__ W2,
                                               float* __restrict__ G) {
    __shared__ float hs[32][128];
    __shared__ float w2s[128 * 40];
    int t = threadIdx.x;
    int row0 = blockIdx.x * 32;
#pragma unroll
    for (int i = 0; i < 16; ++i) {
        int idx = t + i * 256;
        int r = idx >> 7, k = idx & 127;
        float v = 0.f;
        if (row0 + r < N_NODES) v = B[(row0 + r) * D1 + k] + b1[k];
        hs[r][k] = v > 0.f ? v : 0.f;
    }
    for (int idx = t; idx < D1 * D2; idx += 256) w2s[idx] = W2[idx];
    __syncthreads();
    for (int oi = t; oi < 32 * D2; oi += 256) {
        int r = oi / D2, c = oi % D2;
        float acc = 0.f;
#pragma unroll
        for (int k = 0; k < 128; ++k) acc += hs[r][k] * w2s[k * D2 + c];
        if (row0 + r < N_NODES) G[(row0 + r) * D2 + c] = acc;
    }
}

// D[r] = sum_j w_j * G[col_j]  — one row per wave, half-wave per edge,
// col-groups cg<10 hold float4 (40 cols).
__global__ __launch_bounds__(256) void spmm2_k(const float* __restrict__ G,
                                               const int* __restrict__ rowptr,
                                               const int* __restrict__ colS,
                                               const float* __restrict__ wS,
                                               float* __restrict__ D) {
    int t = threadIdx.x;
    int r = blockIdx.x * 4 + (t >> 6);
    int lane = t & 63;
    int half = lane >> 5;
    int cg = lane & 31;
    int s = rowptr[r], e = rowptr[r + 1];
    float4 acc = {0.f, 0.f, 0.f, 0.f};
    if (cg < 10) {
#pragma unroll 4
        for (int j = s + half; j < e; j += 2) {
            int c = colS[j];
            float w = wS[j];
            float4 v = *reinterpret_cast<const float4*>(&G[c * D2 + cg * 4]);
            acc.x += w * v.x;
            acc.y += w * v.y;
            acc.z += w * v.z;
            acc.w += w * v.w;
        }
    }
    acc.x += __shfl_xor(acc.x, 32);
    acc.y += __shfl_xor(acc.y, 32);
    acc.z += __shfl_xor(acc.z, 32);
    acc.w += __shfl_xor(acc.w, 32);
    if (half == 0 && cg < 10) *reinterpret_cast<float4*>(&D[r * D2 + cg * 4]) = acc;
}

// out = log_softmax(D + b2)  — one wave per row
__global__ __launch_bounds__(256) void lsm_k(const float* __restrict__ D,
                                             const float* __restrict__ b2,
                                             float* __restrict__ out) {
    int t = threadIdx.x;
    int r = blockIdx.x * 4 + (t >> 6);
    int lane = t & 63;
    float v = (lane < D2) ? D[r * D2 + lane] + b2[lane] : -INFINITY;
    float m = v;
#pragma unroll
    for (int off = 32; off >= 1; off >>= 1) m = fmaxf(m, __shfl_xor(m, off));
    float ex = (lane < D2) ? expf(v - m) : 0.f;
    float sum = ex;
#pragma unroll
    for (int off = 32; off >= 1; off >>= 1) sum += __shfl_xor(sum, off);
    if (lane < D2) out[r * D2 + lane] = v - m - logf(sum);
}

// ---------------------------------------------------------------------------
extern "C" void kernel_launch(void* const* d_in, const int* in_sizes, int n_in,
                              void* d_out, int out_size, void* d_ws, size_t ws_size,
                              hipStream_t stream) {
    const float* x = (const float*)d_in[0];
    const unsigned int* ei = (const unsigned int*)d_in[1];
    const float* ew = (const float*)d_in[2];
    const float* W1 = (const float*)d_in[3];
    const float* b1 = (const float*)d_in[4];
    const float* W2 = (const float*)d_in[5];
    const float* b2 = (const float*)d_in[6];
    float* out = (float*)d_out;

    char* w = (char*)d_ws;
    float* A = (float*)w;                          // 25.6 MB  XW1 (reused as G)
    float* B = (float*)(w + 25600000);             // 25.6 MB  spmm1 out
    float* G = A;                                  // reuse: A dead after spmm1
    float* D = (float*)(w + 51200000);             // 8 MB     spmm2 out
    int* rowptr = (int*)(w + 59200000);            // (N+1)*4
    int* cnt = (int*)(w + 59400448);               // N*4, doubles as offsets
    int* colS = (int*)(w + 59600448);              // E*4
    float* wS = (float*)(w + 66000448);            // E*4
    int* flag = (int*)(w + 72400448);              // 4
    int* tsum = (int*)(w + 72400512);              // NTILE*4
    int* toff = (int*)(w + 72401536);              // NTILE*4

    detect64_k<<<1, 256, 0, stream>>>(ei, flag);
    zero_k<<<(N_NODES + 255) / 256, 256, 0, stream>>>(cnt, N_NODES);
    hist_k<<<4096, 256, 0, stream>>>(ei, flag, cnt);
    scan1_k<<<NTILE, 256, 0, stream>>>(cnt, rowptr, tsum);
    scan2_k<<<1, 256, 0, stream>>>(tsum, toff, &rowptr[N_NODES]);
    scan3_k<<<NTILE, 256, 0, stream>>>(rowptr, toff, cnt);
    scatter_k<<<4096, 256, 0, stream>>>(ei, ew, flag, cnt, colS, wS);

    gemm1_k<<<N_NODES / 16, 256, 0, stream>>>(x, W1, A);
    spmm1_k<<<N_NODES / 4, 256, 0, stream>>>(A, rowptr, colS, wS, B);
    gemm2_k<<<(N_NODES + 31) / 32, 256, 0, stream>>>(B, b1, W2, G);
    spmm2_k<<<N_NODES / 4, 256, 0, stream>>>(G, rowptr, colS, wS, D);
    lsm_k<<<N_NODES / 4, 256, 0, stream>>>(D, b2, out);
}

// Round 3
// 417.924 us; speedup vs baseline: 2.1201x; 1.3424x over previous
//
#include <hip/hip_runtime.h>
#include <math.h>

#define N_NODES 50000
#define N_EDGES 1600000
#define D1 128
#define D2 40
#define BROWS 128                 // rows per bucket
#define NB 391                    // ceil(N_NODES/BROWS)
#define CHUNK 6250                // N_EDGES / 256 (exact)

// ---------------------------------------------------------------------------
// edge_index dtype detection: if the buffer is int64 (little-endian, values
// < 2^31), every odd 32-bit word of the row array is 0.
__global__ void detect64_k(const unsigned int* __restrict__ ei, int* __restrict__ flag) {
    __shared__ int any;
    if (threadIdx.x == 0) any = 0;
    __syncthreads();
    for (int i = threadIdx.x; i < 2048; i += 256) {
        if (ei[2 * i + 1] != 0u) any = 1;
    }
    __syncthreads();
    if (threadIdx.x == 0) flag[0] = any ? 0 : 1;  // 1 == int64 layout
}

__device__ __forceinline__ int edge_row(const unsigned int* ei, int e, int is64) {
    return (int)(is64 ? ei[2 * e] : ei[e]);
}
__device__ __forceinline__ int edge_col(const unsigned int* ei, int e, int is64) {
    return (int)(is64 ? ei[2 * (N_EDGES + e)] : ei[N_EDGES + e]);
}

__global__ void zero_k(int* __restrict__ p, int n) {
    int i = blockIdx.x * blockDim.x + threadIdx.x;
    if (i < n) p[i] = 0;
}

// ---------------------------------------------------------------------------
// Bucket histogram (LDS-aggregated). gbhp is padded: counter b at gbhp[b*16].
__global__ __launch_bounds__(256) void bhist_k(const unsigned int* __restrict__ ei,
                                               const int* __restrict__ flag,
                                               unsigned int* __restrict__ gbhp) {
    __shared__ unsigned int bh[NB];
    int is64 = flag[0];
    int t = threadIdx.x;
    for (int i = t; i < NB; i += 256) bh[i] = 0;
    __syncthreads();
    int e0 = blockIdx.x * CHUNK, e1 = e0 + CHUNK;
    for (int e = e0 + t; e < e1; e += 256) {
        atomicAdd(&bh[edge_row(ei, e, is64) >> 7], 1u);
    }
    __syncthreads();
    for (int i = t; i < NB; i += 256) {
        if (bh[i]) atomicAdd(&gbhp[i * 16], bh[i]);
    }
}

// Scan NB bucket sums -> bbase[0..NB] (exclusive; bbase[NB]=E), init padded cursors.
__global__ __launch_bounds__(512) void bscan_k(const unsigned int* __restrict__ gbhp,
                                               int* __restrict__ bbase,
                                               unsigned int* __restrict__ bcurp) {
    __shared__ unsigned int s[512];
    int t = threadIdx.x;
    unsigned int v = (t < NB) ? gbhp[t * 16] : 0u;
    s[t] = v;
    __syncthreads();
    for (int off = 1; off < 512; off <<= 1) {
        unsigned int add = (t >= off) ? s[t - off] : 0u;
        __syncthreads();
        s[t] += add;
        __syncthreads();
    }
    if (t < NB) {
        unsigned int excl = s[t] - v;
        bbase[t] = (int)excl;
        bcurp[t * 16] = excl;
    }
    if (t == NB - 1) bbase[NB] = (int)s[t];
}

// Phase 1: bin edges into bucket regions as packed 8B records.
// rec.x = (rlocal<<24) | col   (col < 65536, rlocal < 128);  rec.y = w bits.
__global__ __launch_bounds__(256) void bin_k(const unsigned int* __restrict__ ei,
                                             const float* __restrict__ ew,
                                             const int* __restrict__ flag,
                                             unsigned int* __restrict__ bcurp,
                                             uint2* __restrict__ tmp8) {
    __shared__ unsigned int lh[NB];
    __shared__ unsigned int lcur[NB];
    int is64 = flag[0];
    int t = threadIdx.x;
    for (int i = t; i < NB; i += 256) lh[i] = 0;
    __syncthreads();
    int e0 = blockIdx.x * CHUNK, e1 = e0 + CHUNK;
    for (int e = e0 + t; e < e1; e += 256) {
        atomicAdd(&lh[edge_row(ei, e, is64) >> 7], 1u);
    }
    __syncthreads();
    for (int i = t; i < NB; i += 256) {
        if (lh[i]) lcur[i] = atomicAdd(&bcurp[i * 16], lh[i]);
    }
    __syncthreads();
    for (int e = e0 + t; e < e1; e += 256) {
        int r = edge_row(ei, e, is64);
        int c = edge_col(ei, e, is64);
        int b = r >> 7;
        unsigned int p = atomicAdd(&lcur[b], 1u);
        uint2 rec;
        rec.x = ((unsigned int)(r & 127) << 24) | (unsigned int)c;
        rec.y = __float_as_uint(ew[e]);
        tmp8[p] = rec;
    }
}

// Phase 2: per-bucket row counts -> rowptr (free!), then in-window scatter.
__global__ __launch_bounds__(256) void csr_k(const uint2* __restrict__ tmp8,
                                             const int* __restrict__ bbase,
                                             int* __restrict__ rowptr,
                                             uint2* __restrict__ colwS) {
    __shared__ unsigned int rcnt[BROWS];
    __shared__ unsigned int loff[BROWS];
    __shared__ unsigned int lcur[BROWS];
    int b = blockIdx.x;
    int t = threadIdx.x;
    int lo = bbase[b], hi = bbase[b + 1];
    int r0 = b * BROWS;
    int nrows = N_NODES - r0;
    if (nrows > BROWS) nrows = BROWS;
    if (t < BROWS) rcnt[t] = 0;
    __syncthreads();
    for (int j = lo + t; j < hi; j += 256) {
        atomicAdd(&rcnt[tmp8[j].x >> 24], 1u);
    }
    __syncthreads();
    if (t < BROWS) loff[t] = rcnt[t];
    __syncthreads();
    for (int off = 1; off < BROWS; off <<= 1) {
        unsigned int add = (t >= off && t < BROWS) ? loff[t - off] : 0u;
        __syncthreads();
        if (t < BROWS) loff[t] += add;
        __syncthreads();
    }
    if (t < BROWS) {
        unsigned int excl = loff[t] - rcnt[t];
        if (t < nrows) rowptr[r0 + t] = lo + (int)excl;
        lcur[t] = (unsigned int)lo + excl;
    }
    if (b == NB - 1 && t == 0) rowptr[N_NODES] = hi;
    __syncthreads();
    for (int j = lo + t; j < hi; j += 256) {
        uint2 rec = tmp8[j];
        unsigned int rl = rec.x >> 24;
        unsigned int p = atomicAdd(&lcur[rl], 1u);
        uint2 cw;
        cw.x = rec.x & 0xFFFFu;
        cw.y = rec.y;
        colwS[p] = cw;
    }
}

// ---------------------------------------------------------------------------
// A = x @ W1   (50000x128 * 128x128), f32 VALU, LDS-tiled.
__global__ __launch_bounds__(256) void gemm1_k(const float* __restrict__ x,
                                               const float* __restrict__ W1,
                                               float* __restrict__ A) {
    __shared__ float xs[16][128];
    __shared__ float ws[32][128];
    int t = threadIdx.x;
    int row0 = blockIdx.x * 16;
#pragma unroll
    for (int i = 0; i < 8; ++i) {
        int idx = t + i * 256;
        xs[idx >> 7][idx & 127] = x[(row0 + (idx >> 7)) * D1 + (idx & 127)];
    }
    int c = t & 127;
    int rg = (t >> 7) * 8;
    float acc[8] = {0, 0, 0, 0, 0, 0, 0, 0};
    for (int kb = 0; kb < 128; kb += 32) {
        __syncthreads();
#pragma unroll
        for (int i = 0; i < 16; ++i) {
            int idx = t + i * 256;
            ws[idx >> 7][idx & 127] = W1[(kb + (idx >> 7)) * D1 + (idx & 127)];
        }
        __syncthreads();
#pragma unroll
        for (int k = 0; k < 32; ++k) {
            float w = ws[k][c];
#pragma unroll
            for (int r = 0; r < 8; ++r) acc[r] += xs[rg + r][kb + k] * w;
        }
    }
#pragma unroll
    for (int r = 0; r < 8; ++r) A[(row0 + rg + r) * D1 + c] = acc[r];
}

// B[r] = sum_j w_j * A[col_j]  — one row/wave, half-wave per edge, float4 gathers.
__global__ __launch_bounds__(256) void spmm1_k(const float* __restrict__ A,
                                               const int* __restrict__ rowptr,
                                               const uint2* __restrict__ colwS,
                                               float* __restrict__ B) {
    int t = threadIdx.x;
    int r = blockIdx.x * 4 + (t >> 6);
    int lane = t & 63;
    int half = lane >> 5;
    int cg = lane & 31;
    int s = rowptr[r], e = rowptr[r + 1];
    float4 acc = {0.f, 0.f, 0.f, 0.f};
#pragma unroll 4
    for (int j = s + half; j < e; j += 2) {
        uint2 cw = colwS[j];
        float w = __uint_as_float(cw.y);
        float4 v = *reinterpret_cast<const float4*>(&A[cw.x * D1 + cg * 4]);
        acc.x += w * v.x;
        acc.y += w * v.y;
        acc.z += w * v.z;
        acc.w += w * v.w;
    }
    acc.x += __shfl_xor(acc.x, 32);
    acc.y += __shfl_xor(acc.y, 32);
    acc.z += __shfl_xor(acc.z, 32);
    acc.w += __shfl_xor(acc.w, 32);
    if (half == 0) *reinterpret_cast<float4*>(&B[r * D1 + cg * 4]) = acc;
}

// G = relu(B + b1) @ W2   (bias1 + relu fused into the LDS load)
__global__ __launch_bounds__(256) void gemm2_k(const float* __restrict__ B,
                                               const float* __restrict__ b1,
                                               const float* __restrict__ W2,
                                               float* __restrict__ G) {
    __shared__ float hs[32][128];
    __shared__ float w2s[128 * 40];
    int t = threadIdx.x;
    int row0 = blockIdx.x * 32;
#pragma unroll
    for (int i = 0; i < 16; ++i) {
        int idx = t + i * 256;
        int r = idx >> 7, k = idx & 127;
        float v = 0.f;
        if (row0 + r < N_NODES) v = B[(row0 + r) * D1 + k] + b1[k];
        hs[r][k] = v > 0.f ? v : 0.f;
    }
    for (int idx = t; idx < D1 * D2; idx += 256) w2s[idx] = W2[idx];
    __syncthreads();
    for (int oi = t; oi < 32 * D2; oi += 256) {
        int r = oi / D2, c = oi % D2;
        float acc = 0.f;
#pragma unroll
        for (int k = 0; k < 128; ++k) acc += hs[r][k] * w2s[k * D2 + c];
        if (row0 + r < N_NODES) G[(row0 + r) * D2 + c] = acc;
    }
}

// D[r] = sum_j w_j * G[col_j]  — one row/wave, half-wave per edge, 10 col-groups.
__global__ __launch_bounds__(256) void spmm2_k(const float* __restrict__ G,
                                               const int* __restrict__ rowptr,
                                               const uint2* __restrict__ colwS,
                                               float* __restrict__ D) {
    int t = threadIdx.x;
    int r = blockIdx.x * 4 + (t >> 6);
    int lane = t & 63;
    int half = lane >> 5;
    int cg = lane & 31;
    int s = rowptr[r], e = rowptr[r + 1];
    float4 acc = {0.f, 0.f, 0.f, 0.f};
    if (cg < 10) {
#pragma unroll 4
        for (int j = s + half; j < e; j += 2) {
            uint2 cw = colwS[j];
            float w = __uint_as_float(cw.y);
            float4 v = *reinterpret_cast<const float4*>(&G[cw.x * D2 + cg * 4]);
            acc.x += w * v.x;
            acc.y += w * v.y;
            acc.z += w * v.z;
            acc.w += w * v.w;
        }
    }
    acc.x += __shfl_xor(acc.x, 32);
    acc.y += __shfl_xor(acc.y, 32);
    acc.z += __shfl_xor(acc.z, 32);
    acc.w += __shfl_xor(acc.w, 32);
    if (half == 0 && cg < 10) *reinterpret_cast<float4*>(&D[r * D2 + cg * 4]) = acc;
}

// out = log_softmax(D + b2)  — one wave per row
__global__ __launch_bounds__(256) void lsm_k(const float* __restrict__ D,
                                             const float* __restrict__ b2,
                                             float* __restrict__ out) {
    int t = threadIdx.x;
    int r = blockIdx.x * 4 + (t >> 6);
    int lane = t & 63;
    float v = (lane < D2) ? D[r * D2 + lane] + b2[lane] : -INFINITY;
    float m = v;
#pragma unroll
    for (int off = 32; off >= 1; off >>= 1) m = fmaxf(m, __shfl_xor(m, off));
    float ex = (lane < D2) ? expf(v - m) : 0.f;
    float sum = ex;
#pragma unroll
    for (int off = 32; off >= 1; off >>= 1) sum += __shfl_xor(sum, off);
    if (lane < D2) out[r * D2 + lane] = v - m - logf(sum);
}

// ---------------------------------------------------------------------------
extern "C" void kernel_launch(void* const* d_in, const int* in_sizes, int n_in,
                              void* d_out, int out_size, void* d_ws, size_t ws_size,
                              hipStream_t stream) {
    const float* x = (const float*)d_in[0];
    const unsigned int* ei = (const unsigned int*)d_in[1];
    const float* ew = (const float*)d_in[2];
    const float* W1 = (const float*)d_in[3];
    const float* b1 = (const float*)d_in[4];
    const float* W2 = (const float*)d_in[5];
    const float* b2 = (const float*)d_in[6];
    float* out = (float*)d_out;

    char* w = (char*)d_ws;
    float* A = (float*)w;                          // 25.6 MB  XW1 (reused as G)
    float* B = (float*)(w + 25600000);             // 25.6 MB  spmm1 out
    uint2* tmp8 = (uint2*)(w + 25600000);          //   union with B: tmp8 dead before spmm1 writes B
    float* G = A;                                  // reuse: A dead after spmm1
    float* D = (float*)(w + 51200000);             // 8 MB     spmm2 out
    uint2* colwS = (uint2*)(w + 59200000);         // 12.8 MB  {col, w} per edge (CSR order)
    int* rowptr = (int*)(w + 72000000);            // (N+1)*4
    int* bbase = (int*)(w + 72200064);             // (NB+1)*4
    unsigned int* bcurp = (unsigned int*)(w + 72201664);   // NB*64 padded cursors
    unsigned int* gbhp = (unsigned int*)(w + 72226752);    // NB*64 padded counters
    int* flag = (int*)(w + 72251840);              // 4

    detect64_k<<<1, 256, 0, stream>>>(ei, flag);
    zero_k<<<25, 256, 0, stream>>>((int*)gbhp, NB * 16);
    bhist_k<<<256, 256, 0, stream>>>(ei, flag, gbhp);
    bscan_k<<<1, 512, 0, stream>>>(gbhp, bbase, bcurp);
    bin_k<<<256, 256, 0, stream>>>(ei, ew, flag, bcurp, tmp8);
    csr_k<<<NB, 256, 0, stream>>>(tmp8, bbase, rowptr, colwS);

    gemm1_k<<<N_NODES / 16, 256, 0, stream>>>(x, W1, A);
    spmm1_k<<<N_NODES / 4, 256, 0, stream>>>(A, rowptr, colwS, B);
    gemm2_k<<<(N_NODES + 31) / 32, 256, 0, stream>>>(B, b1, W2, G);
    spmm2_k<<<N_NODES / 4, 256, 0, stream>>>(G, rowptr, colwS, D);
    lsm_k<<<N_NODES / 4, 256, 0, stream>>>(D, b2, out);
}

// Round 4
// 330.115 us; speedup vs baseline: 2.6840x; 1.2660x over previous
//
#include <hip/hip_runtime.h>
#include <math.h>

#define N_NODES 50000
#define N_EDGES 1600000
#define D1 128
#define D2 40
#define BROWS 128                 // rows per bucket
#define NB 391                    // ceil(N_NODES/BROWS)
#define CHUNK 6250                // N_EDGES / 256 (exact)
#define NSEG 7                    // column segments (col>>13), 8192 rows = 4.2MB of A
#define NKEY (BROWS * NSEG)       // 896 sort keys in csr_k

typedef __attribute__((ext_vector_type(8))) short bf16x8;
typedef __attribute__((ext_vector_type(4))) float f32x4;

// split f32 -> bf16 hi + bf16 lo (RNE both); x ~= hi + lo with ~2^-16 rel err
__device__ __forceinline__ void bf16_split(float v, unsigned short& h, unsigned short& l) {
    unsigned u = __float_as_uint(v);
    unsigned r = u + 0x7fffu + ((u >> 16) & 1u);
    h = (unsigned short)(r >> 16);
    float hf = __uint_as_float((unsigned)h << 16);
    float lof = v - hf;
    unsigned u2 = __float_as_uint(lof);
    unsigned r2 = u2 + 0x7fffu + ((u2 >> 16) & 1u);
    l = (unsigned short)(r2 >> 16);
}

// ---------------------------------------------------------------------------
__global__ void detect64_k(const unsigned int* __restrict__ ei, int* __restrict__ flag) {
    __shared__ int any;
    if (threadIdx.x == 0) any = 0;
    __syncthreads();
    for (int i = threadIdx.x; i < 2048; i += 256) {
        if (ei[2 * i + 1] != 0u) any = 1;
    }
    __syncthreads();
    if (threadIdx.x == 0) flag[0] = any ? 0 : 1;  // 1 == int64 layout
}

__device__ __forceinline__ int edge_row(const unsigned int* ei, int e, int is64) {
    return (int)(is64 ? ei[2 * e] : ei[e]);
}
__device__ __forceinline__ int edge_col(const unsigned int* ei, int e, int is64) {
    return (int)(is64 ? ei[2 * (N_EDGES + e)] : ei[N_EDGES + e]);
}

__global__ void zero_k(int* __restrict__ p, int n) {
    int i = blockIdx.x * blockDim.x + threadIdx.x;
    if (i < n) p[i] = 0;
}

// ---------------------------------------------------------------------------
// Bucket histogram (LDS-aggregated). gbhp is padded: counter b at gbhp[b*16].
__global__ __launch_bounds__(256) void bhist_k(const unsigned int* __restrict__ ei,
                                               const int* __restrict__ flag,
                                               unsigned int* __restrict__ gbhp) {
    __shared__ unsigned int bh[NB];
    int is64 = flag[0];
    int t = threadIdx.x;
    for (int i = t; i < NB; i += 256) bh[i] = 0;
    __syncthreads();
    int e0 = blockIdx.x * CHUNK, e1 = e0 + CHUNK;
    for (int e = e0 + t; e < e1; e += 256) {
        atomicAdd(&bh[edge_row(ei, e, is64) >> 7], 1u);
    }
    __syncthreads();
    for (int i = t; i < NB; i += 256) {
        if (bh[i]) atomicAdd(&gbhp[i * 16], bh[i]);
    }
}

__global__ __launch_bounds__(512) void bscan_k(const unsigned int* __restrict__ gbhp,
                                               int* __restrict__ bbase,
                                               unsigned int* __restrict__ bcurp) {
    __shared__ unsigned int s[512];
    int t = threadIdx.x;
    unsigned int v = (t < NB) ? gbhp[t * 16] : 0u;
    s[t] = v;
    __syncthreads();
    for (int off = 1; off < 512; off <<= 1) {
        unsigned int add = (t >= off) ? s[t - off] : 0u;
        __syncthreads();
        s[t] += add;
        __syncthreads();
    }
    if (t < NB) {
        unsigned int excl = s[t] - v;
        bbase[t] = (int)excl;
        bcurp[t * 16] = excl;
    }
    if (t == NB - 1) bbase[NB] = (int)s[t];
}

// Phase 1: bin edges into bucket regions as packed 8B records.
// rec.x = (rlocal<<24) | col;  rec.y = w bits.
__global__ __launch_bounds__(256) void bin_k(const unsigned int* __restrict__ ei,
                                             const float* __restrict__ ew,
                                             const int* __restrict__ flag,
                                             unsigned int* __restrict__ bcurp,
                                             uint2* __restrict__ tmp8) {
    __shared__ unsigned int lh[NB];
    __shared__ unsigned int lcur[NB];
    int is64 = flag[0];
    int t = threadIdx.x;
    for (int i = t; i < NB; i += 256) lh[i] = 0;
    __syncthreads();
    int e0 = blockIdx.x * CHUNK, e1 = e0 + CHUNK;
    for (int e = e0 + t; e < e1; e += 256) {
        atomicAdd(&lh[edge_row(ei, e, is64) >> 7], 1u);
    }
    __syncthreads();
    for (int i = t; i < NB; i += 256) {
        if (lh[i]) lcur[i] = atomicAdd(&bcurp[i * 16], lh[i]);
    }
    __syncthreads();
    for (int e = e0 + t; e < e1; e += 256) {
        int r = edge_row(ei, e, is64);
        int c = edge_col(ei, e, is64);
        int b = r >> 7;
        unsigned int p = atomicAdd(&lcur[b], 1u);
        uint2 rec;
        rec.x = ((unsigned int)(r & 127) << 24) | (unsigned int)c;
        rec.y = __float_as_uint(ew[e]);
        tmp8[p] = rec;
    }
}

// Phase 2: counting-sort the bucket window by key (rlocal, col>>13).
// rowptr falls out of the key scan; column-segment order gives spmm phase locality.
__global__ __launch_bounds__(256) void csr_k(const uint2* __restrict__ tmp8,
                                             const int* __restrict__ bbase,
                                             int* __restrict__ rowptr,
                                             uint2* __restrict__ colwS) {
    __shared__ unsigned int kcnt[NKEY];
    __shared__ unsigned int lcur[NKEY];
    __shared__ unsigned int ssum[256];
    int b = blockIdx.x;
    int t = threadIdx.x;
    int lo = bbase[b], hi = bbase[b + 1];
    int r0 = b * BROWS;
    int nrows = N_NODES - r0;
    if (nrows > BROWS) nrows = BROWS;
    for (int i = t; i < NKEY; i += 256) kcnt[i] = 0;
    __syncthreads();
    for (int j = lo + t; j < hi; j += 256) {
        unsigned int rx = tmp8[j].x;
        unsigned int key = (rx >> 24) * NSEG + ((rx & 0xffffu) >> 13);
        atomicAdd(&kcnt[key], 1u);
    }
    __syncthreads();
    // exclusive scan of kcnt[0..NKEY): thread t owns keys 4t..4t+3
    unsigned int lsum = 0;
    if (t < NKEY / 4) {
#pragma unroll
        for (int je = 0; je < 4; ++je) lsum += kcnt[t * 4 + je];
    }
    ssum[t] = lsum;
    __syncthreads();
    for (int off = 1; off < 256; off <<= 1) {
        unsigned int add = (t >= off) ? ssum[t - off] : 0u;
        __syncthreads();
        ssum[t] += add;
        __syncthreads();
    }
    unsigned int run = (t == 0) ? 0u : ssum[t - 1];
    if (t < NKEY / 4) {
#pragma unroll
        for (int je = 0; je < 4; ++je) {
            unsigned int c = kcnt[t * 4 + je];
            lcur[t * 4 + je] = run;
            run += c;
        }
    }
    __syncthreads();
    if (t < nrows) rowptr[r0 + t] = lo + (int)lcur[t * NSEG];
    if (b == NB - 1 && t == 0) rowptr[N_NODES] = hi;
    __syncthreads();
    for (int j = lo + t; j < hi; j += 256) {
        uint2 rec = tmp8[j];
        unsigned int key = (rec.x >> 24) * NSEG + ((rec.x & 0xffffu) >> 13);
        unsigned int p = atomicAdd(&lcur[key], 1u);
        uint2 cw;
        cw.x = rec.x & 0xffffu;
        cw.y = rec.y;
        colwS[lo + p] = cw;
    }
}

// ---------------------------------------------------------------------------
// Pack W1 (f32 [128][128]) into MFMA B-fragment order, split hi/lo bf16.
// frag(nt, ks): lane l holds B[ks*32 + (l>>4)*8 + j][nt*16 + (l&15)], j=0..7.
__global__ __launch_bounds__(256) void packw1_k(const float* __restrict__ W1,
                                                unsigned short* __restrict__ wh,
                                                unsigned short* __restrict__ wl) {
    int idx = blockIdx.x * 256 + threadIdx.x;  // 16384
    int k = idx >> 7, n = idx & 127;
    unsigned short h, l;
    bf16_split(W1[k * 128 + n], h, l);
    int nt = n >> 4, ks = k >> 5;
    int lane = (n & 15) | (((k >> 3) & 3) << 4);
    int j = k & 7;
    int dst = ((nt * 4 + ks) * 64 + lane) * 8 + j;
    wh[dst] = h;
    wl[dst] = l;
}

// Pack W2 (f32 [128][40], zero-padded to 48 cols) the same way: 3 n-tiles.
__global__ __launch_bounds__(256) void packw2_k(const float* __restrict__ W2,
                                                unsigned short* __restrict__ wh,
                                                unsigned short* __restrict__ wl) {
    int idx = blockIdx.x * 256 + threadIdx.x;  // 6144
    int k = idx / 48, n = idx % 48;
    float v = (n < 40) ? W2[k * 40 + n] : 0.f;
    unsigned short h, l;
    bf16_split(v, h, l);
    int nt = n >> 4, ks = k >> 5;
    int lane = (n & 15) | (((k >> 3) & 3) << 4);
    int j = k & 7;
    int dst = ((nt * 4 + ks) * 64 + lane) * 8 + j;
    wh[dst] = h;
    wl[dst] = l;
}

// A = x @ W1 via mfma_f32_16x16x32_bf16, split-bf16 3-pass (hh + hl + lh).
// Block = 4 waves x 16 rows = 64 rows, full N=128.
__global__ __launch_bounds__(256) void gemm1_k(const float* __restrict__ x,
                                               const unsigned short* __restrict__ wh,
                                               const unsigned short* __restrict__ wl,
                                               float* __restrict__ A) {
    int t = threadIdx.x;
    int w = t >> 6, l = t & 63;
    int row0 = blockIdx.x * 64 + w * 16;
    int arow = row0 + (l & 15);
    if (arow > N_NODES - 1) arow = N_NODES - 1;
    int kbase = (l >> 4) * 8;
    bf16x8 ah[4], al[4];
#pragma unroll
    for (int ks = 0; ks < 4; ++ks) {
        const float* px = &x[arow * D1 + ks * 32 + kbase];
        float4 v0 = *reinterpret_cast<const float4*>(px);
        float4 v1 = *reinterpret_cast<const float4*>(px + 4);
        float vv[8] = {v0.x, v0.y, v0.z, v0.w, v1.x, v1.y, v1.z, v1.w};
#pragma unroll
        for (int j = 0; j < 8; ++j) {
            unsigned short h, lo2;
            bf16_split(vv[j], h, lo2);
            ah[ks][j] = (short)h;
            al[ks][j] = (short)lo2;
        }
    }
    f32x4 acc[8];
#pragma unroll
    for (int nt = 0; nt < 8; ++nt) acc[nt] = (f32x4)(0.f);
#pragma unroll
    for (int nt = 0; nt < 8; ++nt) {
#pragma unroll
        for (int ks = 0; ks < 4; ++ks) {
            int fo = ((nt * 4 + ks) * 64 + l) * 8;
            bf16x8 bh = *reinterpret_cast<const bf16x8*>(&wh[fo]);
            bf16x8 bl = *reinterpret_cast<const bf16x8*>(&wl[fo]);
            acc[nt] = __builtin_amdgcn_mfma_f32_16x16x32_bf16(ah[ks], bh, acc[nt], 0, 0, 0);
            acc[nt] = __builtin_amdgcn_mfma_f32_16x16x32_bf16(ah[ks], bl, acc[nt], 0, 0, 0);
            acc[nt] = __builtin_amdgcn_mfma_f32_16x16x32_bf16(al[ks], bh, acc[nt], 0, 0, 0);
        }
    }
    int crow0 = row0 + (l >> 4) * 4;
    int ccol = l & 15;
#pragma unroll
    for (int nt = 0; nt < 8; ++nt) {
#pragma unroll
        for (int r = 0; r < 4; ++r) {
            int rr = crow0 + r;
            if (rr < N_NODES) A[rr * D1 + nt * 16 + ccol] = acc[nt][r];
        }
    }
}

// B[r] = sum_j w_j * A[col_j]  — one row/wave, half-wave per edge, float4 gathers.
// Edges are column-segment sorted -> concurrent waves share an L2-resident segment.
__global__ __launch_bounds__(256) void spmm1_k(const float* __restrict__ A,
                                               const int* __restrict__ rowptr,
                                               const uint2* __restrict__ colwS,
                                               float* __restrict__ B) {
    int t = threadIdx.x;
    int r = blockIdx.x * 4 + (t >> 6);
    int lane = t & 63;
    int half = lane >> 5;
    int cg = lane & 31;
    int s = rowptr[r], e = rowptr[r + 1];
    float4 acc = {0.f, 0.f, 0.f, 0.f};
#pragma unroll 4
    for (int j = s + half; j < e; j += 2) {
        uint2 cw = colwS[j];
        float w = __uint_as_float(cw.y);
        float4 v = *reinterpret_cast<const float4*>(&A[cw.x * D1 + cg * 4]);
        acc.x += w * v.x;
        acc.y += w * v.y;
        acc.z += w * v.z;
        acc.w += w * v.w;
    }
    acc.x += __shfl_xor(acc.x, 32);
    acc.y += __shfl_xor(acc.y, 32);
    acc.z += __shfl_xor(acc.z, 32);
    acc.w += __shfl_xor(acc.w, 32);
    if (half == 0) *reinterpret_cast<float4*>(&B[r * D1 + cg * 4]) = acc;
}

// G = relu(B + b1) @ W2 via MFMA split-bf16 (N padded 40->48, 3 n-tiles).
__global__ __launch_bounds__(256) void gemm2_k(const float* __restrict__ Bm,
                                               const float* __restrict__ b1,
                                               const unsigned short* __restrict__ wh,
                                               const unsigned short* __restrict__ wl,
                                               float* __restrict__ G) {
    int t = threadIdx.x;
    int w = t >> 6, l = t & 63;
    int row0 = blockIdx.x * 64 + w * 16;
    int arow = row0 + (l & 15);
    if (arow > N_NODES - 1) arow = N_NODES - 1;
    int kbase = (l >> 4) * 8;
    bf16x8 ah[4], al[4];
#pragma unroll
    for (int ks = 0; ks < 4; ++ks) {
        const float* pb = &Bm[arow * D1 + ks * 32 + kbase];
        const float* pb1 = &b1[ks * 32 + kbase];
        float4 v0 = *reinterpret_cast<const float4*>(pb);
        float4 v1 = *reinterpret_cast<const float4*>(pb + 4);
        float4 c0 = *reinterpret_cast<const float4*>(pb1);
        float4 c1 = *reinterpret_cast<const float4*>(pb1 + 4);
        float vv[8] = {v0.x + c0.x, v0.y + c0.y, v0.z + c0.z, v0.w + c0.w,
                       v1.x + c1.x, v1.y + c1.y, v1.z + c1.z, v1.w + c1.w};
#pragma unroll
        for (int j = 0; j < 8; ++j) {
            float rv = vv[j] > 0.f ? vv[j] : 0.f;
            unsigned short h, lo2;
            bf16_split(rv, h, lo2);
            ah[ks][j] = (short)h;
            al[ks][j] = (short)lo2;
        }
    }
    f32x4 acc[3];
#pragma unroll
    for (int nt = 0; nt < 3; ++nt) acc[nt] = (f32x4)(0.f);
#pragma unroll
    for (int nt = 0; nt < 3; ++nt) {
#pragma unroll
        for (int ks = 0; ks < 4; ++ks) {
            int fo = ((nt * 4 + ks) * 64 + l) * 8;
            bf16x8 bh = *reinterpret_cast<const bf16x8*>(&wh[fo]);
            bf16x8 bl = *reinterpret_cast<const bf16x8*>(&wl[fo]);
            acc[nt] = __builtin_amdgcn_mfma_f32_16x16x32_bf16(ah[ks], bh, acc[nt], 0, 0, 0);
            acc[nt] = __builtin_amdgcn_mfma_f32_16x16x32_bf16(ah[ks], bl, acc[nt], 0, 0, 0);
            acc[nt] = __builtin_amdgcn_mfma_f32_16x16x32_bf16(al[ks], bh, acc[nt], 0, 0, 0);
        }
    }
    int crow0 = row0 + (l >> 4) * 4;
    int ccol = l & 15;
#pragma unroll
    for (int nt = 0; nt < 3; ++nt) {
        int col = nt * 16 + ccol;
        if (col < D2) {
#pragma unroll
            for (int r = 0; r < 4; ++r) {
                int rr = crow0 + r;
                if (rr < N_NODES) G[rr * D2 + col] = acc[nt][r];
            }
        }
    }
}

// out[r] = log_softmax(sum_j w_j * G[col_j] + b2) — one wave per row.
// 6 edges x 10 lanes (float4 each) per iteration; softmax fused in-wave.
__global__ __launch_bounds__(256) void spmm2lsm_k(const float* __restrict__ G,
                                                  const int* __restrict__ rowptr,
                                                  const uint2* __restrict__ colwS,
                                                  const float* __restrict__ b2,
                                                  float* __restrict__ out) {
    int t = threadIdx.x;
    int r = blockIdx.x * 4 + (t >> 6);
    int lane = t & 63;
    int slot = lane / 10;   // 0..5 active, 6 for lanes 60..63 (inactive)
    int comp = lane % 10;   // float4 group: cols comp*4..comp*4+3
    int s = rowptr[r], e = rowptr[r + 1];
    float4 acc = {0.f, 0.f, 0.f, 0.f};
    bool act = lane < 60;
#pragma unroll 2
    for (int j0 = s; j0 < e; j0 += 6) {
        int j = j0 + slot;
        if (act && j < e) {
            uint2 cw = colwS[j];
            float w = __uint_as_float(cw.y);
            float4 v = *reinterpret_cast<const float4*>(&G[cw.x * D2 + comp * 4]);
            acc.x += w * v.x;
            acc.y += w * v.y;
            acc.z += w * v.z;
            acc.w += w * v.w;
        }
    }
    // reduce 6 slots -> lanes 0..9
    acc.x += __shfl_down(acc.x, 30);
    acc.y += __shfl_down(acc.y, 30);
    acc.z += __shfl_down(acc.z, 30);
    acc.w += __shfl_down(acc.w, 30);
    {
        float t1 = __shfl_down(acc.x, 10), t2 = __shfl_down(acc.x, 20);
        acc.x += t1 + t2;
        t1 = __shfl_down(acc.y, 10); t2 = __shfl_down(acc.y, 20);
        acc.y += t1 + t2;
        t1 = __shfl_down(acc.z, 10); t2 = __shfl_down(acc.z, 20);
        acc.z += t1 + t2;
        t1 = __shfl_down(acc.w, 10); t2 = __shfl_down(acc.w, 20);
        acc.w += t1 + t2;
    }
    bool valid = lane < 10;
    float4 bv = *reinterpret_cast<const float4*>(&b2[comp * 4]);
    float4 v4;
    v4.x = valid ? acc.x + bv.x : -INFINITY;
    v4.y = valid ? acc.y + bv.y : -INFINITY;
    v4.z = valid ? acc.z + bv.z : -INFINITY;
    v4.w = valid ? acc.w + bv.w : -INFINITY;
    float m = fmaxf(fmaxf(v4.x, v4.y), fmaxf(v4.z, v4.w));
#pragma unroll
    for (int off = 1; off < 16; off <<= 1) m = fmaxf(m, __shfl_xor(m, off));
    float ex = (valid ? expf(v4.x - m) + expf(v4.y - m) + expf(v4.z - m) + expf(v4.w - m) : 0.f);
#pragma unroll
    for (int off = 1; off < 16; off <<= 1) ex += __shfl_xor(ex, off);
    float lse = m + logf(ex);
    if (valid) {
        float4 o;
        o.x = v4.x - lse;
        o.y = v4.y - lse;
        o.z = v4.z - lse;
        o.w = v4.w - lse;
        *reinterpret_cast<float4*>(&out[r * D2 + comp * 4]) = o;
    }
}

// ---------------------------------------------------------------------------
extern "C" void kernel_launch(void* const* d_in, const int* in_sizes, int n_in,
                              void* d_out, int out_size, void* d_ws, size_t ws_size,
                              hipStream_t stream) {
    const float* x = (const float*)d_in[0];
    const unsigned int* ei = (const unsigned int*)d_in[1];
    const float* ew = (const float*)d_in[2];
    const float* W1 = (const float*)d_in[3];
    const float* b1 = (const float*)d_in[4];
    const float* W2 = (const float*)d_in[5];
    const float* b2 = (const float*)d_in[6];
    float* out = (float*)d_out;

    char* w = (char*)d_ws;
    float* A = (float*)w;                          // 25.6 MB  XW1; reused as G after spmm1
    float* B = (float*)(w + 25600000);             // 25.6 MB  spmm1 out
    uint2* tmp8 = (uint2*)(w + 25600000);          //   union with B (tmp8 dead before spmm1)
    float* G = A;
    uint2* colwS = (uint2*)(w + 51200000);         // 12.8 MB  {col, w} CSR order, ends 64,000,000
    int* rowptr = (int*)(w + 64000000);            // (N+1)*4
    int* bbase = (int*)(w + 64200064);             // (NB+1)*4
    unsigned int* bcurp = (unsigned int*)(w + 64201664);   // NB*64
    unsigned int* gbhp = (unsigned int*)(w + 64226688);    // NB*64
    int* flag = (int*)(w + 64251712);              // 4
    unsigned short* wh1 = (unsigned short*)(w + 64251776); // 32 KB
    unsigned short* wl1 = (unsigned short*)(w + 64284544); // 32 KB
    unsigned short* wh2 = (unsigned short*)(w + 64317312); // 12 KB
    unsigned short* wl2 = (unsigned short*)(w + 64329600); // 12 KB -> ends 64,341,888

    detect64_k<<<1, 256, 0, stream>>>(ei, flag);
    zero_k<<<25, 256, 0, stream>>>((int*)gbhp, NB * 16);
    packw1_k<<<64, 256, 0, stream>>>(W1, wh1, wl1);
    packw2_k<<<24, 256, 0, stream>>>(W2, wh2, wl2);
    bhist_k<<<256, 256, 0, stream>>>(ei, flag, gbhp);
    bscan_k<<<1, 512, 0, stream>>>(gbhp, bbase, bcurp);
    bin_k<<<256, 256, 0, stream>>>(ei, ew, flag, bcurp, tmp8);
    csr_k<<<NB, 256, 0, stream>>>(tmp8, bbase, rowptr, colwS);

    gemm1_k<<<782, 256, 0, stream>>>(x, wh1, wl1, A);
    spmm1_k<<<N_NODES / 4, 256, 0, stream>>>(A, rowptr, colwS, B);
    gemm2_k<<<782, 256, 0, stream>>>(B, b1, wh2, wl2, G);
    spmm2lsm_k<<<N_NODES / 4, 256, 0, stream>>>(G, rowptr, colwS, b2, out);
}